// Round 15
// baseline (316.899 us; speedup 1.0000x reference)
//
#include <hip/hip_runtime.h>
#include <hip/hip_bf16.h>
#include <math.h>

#define CCH 320
#define NHEADS 8
#define DH 40
#define HW 4096
#define FFI 1280

typedef __bf16 bf16x8 __attribute__((ext_vector_type(8)));
typedef unsigned short u16x8 __attribute__((ext_vector_type(8)));
typedef short s16x4 __attribute__((ext_vector_type(4)));
typedef float f32x4 __attribute__((ext_vector_type(4)));
typedef unsigned int u32x4 __attribute__((ext_vector_type(4)));

__device__ inline unsigned short f2bf(float f) {
    __hip_bfloat16 h = __float2bfloat16(f);
    return __builtin_bit_cast(unsigned short, h);
}
__device__ inline unsigned pk2bf(float a, float b) {
#if __has_builtin(__builtin_amdgcn_cvt_pk_bf16_f32)
    typedef __bf16 bf16x2 __attribute__((ext_vector_type(2)));
    bf16x2 r = __builtin_amdgcn_cvt_pk_bf16_f32(a, b);
    return __builtin_bit_cast(unsigned, r);
#else
    return (unsigned)f2bf(a) | ((unsigned)f2bf(b) << 16);
#endif
}
__device__ inline float bf2f(unsigned short u) {
    return __builtin_bit_cast(float, ((unsigned)u) << 16);
}
__device__ inline bf16x8 ldfrag(const unsigned short* p) {
    u16x8 raw = *reinterpret_cast<const u16x8*>(p);
    return __builtin_bit_cast(bf16x8, raw);
}
__device__ inline s16x4 pk2frag(unsigned a, unsigned b) {
    unsigned long long v = (unsigned long long)a | ((unsigned long long)b << 32);
    return __builtin_bit_cast(s16x4, v);
}

// ---------------------------------------------------------------------------
// Coalesced weight transpose via LDS 64x65 tiles. 620 tiles.
__global__ __launch_bounds__(256) void prep_w2(
    const float* __restrict__ w_in, const float* __restrict__ wq1,
    const float* __restrict__ wk1, const float* __restrict__ wv1,
    const float* __restrict__ wo1, const float* __restrict__ wq2,
    const float* __restrict__ wo2, const float* __restrict__ w_out,
    const float* __restrict__ wff1, const float* __restrict__ wff2,
    const float* __restrict__ wk2, const float* __restrict__ wv2,
    unsigned short* __restrict__ Wt) {
    __shared__ float tile[64][65];
    const int b = blockIdx.x, tid = threadIdx.x;
    const float* src;
    int K, stride, dstoff, k0, n0;
    bool glu = false;
    if (b < 200) {
        int m = b / 25, t = b % 25;
        k0 = (t / 5) * 64; n0 = (t % 5) * 64;
        K = 320; stride = 320; dstoff = m * 102400;
        src = (m == 0) ? w_in : (m == 1) ? wq1 : (m == 2) ? wk1 :
              (m == 3) ? wv1 : (m == 4) ? wo1 : (m == 5) ? wq2 :
              (m == 6) ? wo2 : w_out;
    } else if (b < 300) {
        int t = b - 200;
        k0 = (t / 5) * 64; n0 = (t % 5) * 64;
        K = 1280; stride = 320; dstoff = 1638400; src = wff2;
    } else if (b < 500) {
        int t = b - 300;
        k0 = (t / 40) * 64; n0 = (t % 40) * 64;
        K = 320; stride = 2560; dstoff = 819200; src = wff1; glu = true;
    } else if (b < 560) {
        int t = b - 500;
        k0 = (t / 5) * 64; n0 = (t % 5) * 64;
        K = 768; stride = 320; dstoff = 2048000; src = wk2;
    } else {
        int t = b - 560;
        k0 = (t / 5) * 64; n0 = (t % 5) * 64;
        K = 768; stride = 320; dstoff = 2048000 + 245760; src = wv2;
    }
#pragma unroll
    for (int i = 0; i < 16; ++i) {
        int idx = tid + i * 256;
        int r = idx >> 6, cn = idx & 63;
        int scol = glu ? ((n0 >> 1) + (cn >> 1) + (cn & 1) * FFI) : (n0 + cn);
        tile[r][cn] = src[(size_t)(k0 + r) * stride + scol];
    }
    __syncthreads();
#pragma unroll
    for (int i = 0; i < 16; ++i) {
        int idx = tid + i * 256;
        int cl = idx >> 6, cr = idx & 63;
        Wt[dstoff + (size_t)(n0 + cl) * K + k0 + cr] = f2bf(tile[cr][cl]);
    }
}

// ---------------------------------------------------------------------------
// ctx (77x768 fp32) -> bf16 (128x768), rows >= 77 zeroed.
__global__ void pack_ctx(const float* __restrict__ ctx,
                         unsigned short* __restrict__ D) {
    int idx = blockIdx.x * 256 + threadIdx.x;  // grid 384 -> 98304 exact
    int row = idx / 768, col = idx - row * 768;
    float v = (row < 77) ? ctx[row * 768 + col] : 0.f;
    D[idx] = f2bf(v);
}

// ---------------------------------------------------------------------------
__global__ __launch_bounds__(256) void gn_stats(const float* __restrict__ X,
                                                float2* __restrict__ part) {
    __shared__ float s1[256], s2[256];
    const int b = blockIdx.x, tid = threadIdx.x;
    const float* xg = X + b * 5120;
    float s = 0.f, sq = 0.f;
#pragma unroll
    for (int i = 0; i < 20; ++i) { float v = xg[tid + i * 256]; s += v; sq += v * v; }
    s1[tid] = s; s2[tid] = sq; __syncthreads();
    for (int off = 128; off > 0; off >>= 1) {
        if (tid < off) { s1[tid] += s1[tid + off]; s2[tid] += s2[tid + off]; }
        __syncthreads();
    }
    if (tid == 0) part[b] = make_float2(s1[0], s2[0]);
}

__global__ __launch_bounds__(256) void gn_apply(const float* __restrict__ X,
                                                const float2* __restrict__ part,
                                                const float* __restrict__ w,
                                                const float* __restrict__ b,
                                                unsigned short* __restrict__ Y) {
    __shared__ float tile[64][65];
    __shared__ float gm[32], gr[32];
    const int tid = threadIdx.x;
    const int hw0 = blockIdx.x * 64, c0 = blockIdx.y * 64;
    if (tid < 32) {
        float s = 0.f, sq = 0.f;
#pragma unroll
        for (int i = 0; i < 8; ++i) { float2 p = part[tid * 8 + i]; s += p.x; sq += p.y; }
        float mean = s * (1.f / 40960.f);
        float var  = sq * (1.f / 40960.f) - mean * mean;
        gm[tid] = mean; gr[tid] = rsqrtf(var + 1e-6f);
    }
#pragma unroll
    for (int i = 0; i < 16; ++i) {
        int idx = tid + i * 256;
        int r = idx >> 6, col = idx & 63;
        tile[r][col] = X[(size_t)(c0 + r) * HW + hw0 + col];
    }
    __syncthreads();
#pragma unroll
    for (int i = 0; i < 16; ++i) {
        int idx = tid + i * 256;
        int hwl = idx >> 6, cl = idx & 63;
        int c = c0 + cl, g = c / 10;
        float v = (tile[cl][hwl] - gm[g]) * gr[g] * w[c] + b[c];
        Y[(size_t)(hw0 + hwl) * CCH + c] = f2bf(v);
    }
}

// ---------------------------------------------------------------------------
__global__ __launch_bounds__(256) void ln_kernel(const float* __restrict__ X,
                                                 const float* __restrict__ w,
                                                 const float* __restrict__ b,
                                                 unsigned short* __restrict__ Y) {
    const int row  = blockIdx.x * 4 + (threadIdx.x >> 6);
    const int lane = threadIdx.x & 63;
    const float* xr = X + row * CCH;
    float v[5];
    float s = 0.f, sq = 0.f;
#pragma unroll
    for (int i = 0; i < 5; ++i) { v[i] = xr[lane + 64 * i]; s += v[i]; sq += v[i] * v[i]; }
#pragma unroll
    for (int off = 32; off > 0; off >>= 1) {
        s  += __shfl_xor(s, off, 64);
        sq += __shfl_xor(sq, off, 64);
    }
    const float mean = s * (1.f / 320.f);
    const float var  = sq * (1.f / 320.f) - mean * mean;
    const float rstd = rsqrtf(var + 1e-5f);
    unsigned short* yr = Y + row * CCH;
#pragma unroll
    for (int i = 0; i < 5; ++i) {
        int c = lane + 64 * i;
        yr[c] = f2bf((v[i] - mean) * rstd * w[c] + b[c]);
    }
}

// ---------------------------------------------------------------------------
// gemm4: double-buffer GEMM, now with DEPTH-2 software pipeline / 3 LDS
// buffers: iteration ch issues loads for ch+2, computes ch from LDS, writes
// the ch+1 registers (loaded one full iteration earlier -> latency covered).
// Modes: 0 fp32+bias(+res) | 2 QK-pack*scale | 4 bf16+bias+res |
//        5 GLU-interleaved | 6 dual bf16+QK-pack | 7 kv-merged (Lkp=4096) |
//        8 ctx kv-merged (Lkp=128) | 9 transposed fp32 out + x (final fused)
template <int MT, int K>
__global__ __launch_bounds__(256) void gemm4(
    const unsigned short* __restrict__ A,
    const unsigned short* __restrict__ Bt,
    const float* __restrict__ bias,
    const float* __restrict__ res,
    void* __restrict__ Cout, void* __restrict__ Cout2,
    int N, int mode, float scale) {
    constexpr int NCH = K / 64;
    __shared__ __align__(16) unsigned short Ab[3][MT * 16 * 64];
    __shared__ __align__(16) unsigned short Bb[3][64 * 64];
    const int tid  = threadIdx.x;
    const int wave = tid >> 6, lane = tid & 63;
    const int quad = lane >> 4, c = lane & 15;
    const int m0 = blockIdx.y * (MT * 16);
    const int bn = blockIdx.x;

    f32x4 acc[MT];
#pragma unroll
    for (int i = 0; i < MT; ++i) acc[i] = (f32x4){0.f, 0.f, 0.f, 0.f};

    const unsigned short* aslab = A + (size_t)m0 * K;
    const unsigned short* bslab = Bt + (size_t)(bn * 64) * K;

    constexpr int ITA = MT * 16 * 8 / 256;
    int arow[ITA], aoff[ITA];
#pragma unroll
    for (int i = 0; i < ITA; ++i) {
        int idx = tid + i * 256;
        arow[i] = idx >> 3;
        int g = idx & 7;
        aoff[i] = arow[i] * 64 + ((g ^ (arow[i] & 7)) * 8);
    }
    int brow[2], boff[2];
#pragma unroll
    for (int i = 0; i < 2; ++i) {
        int idx = tid + i * 256;
        brow[i] = idx >> 3;
        int g = idx & 7;
        boff[i] = brow[i] * 64 + ((g ^ (brow[i] & 7)) * 8);
    }
    const int ag = (tid & 7) * 8;

    // pending register sets (2-deep rotation)
    u16x8 pa[2][ITA], pb[2][2];

    // prologue: chunk 0 -> buf0 directly; chunk 1 -> set 0
    {
        u16x8 ra[ITA], rb[2];
#pragma unroll
        for (int i = 0; i < ITA; ++i)
            ra[i] = *(const u16x8*)(aslab + (size_t)arow[i] * K + ag);
#pragma unroll
        for (int i = 0; i < 2; ++i)
            rb[i] = *(const u16x8*)(bslab + (size_t)brow[i] * K + ag);
        if (NCH > 1) {
#pragma unroll
            for (int i = 0; i < ITA; ++i)
                pa[0][i] = *(const u16x8*)(aslab + (size_t)arow[i] * K + 64 + ag);
#pragma unroll
            for (int i = 0; i < 2; ++i)
                pb[0][i] = *(const u16x8*)(bslab + (size_t)brow[i] * K + 64 + ag);
        }
#pragma unroll
        for (int i = 0; i < ITA; ++i) *(u16x8*)&Ab[0][aoff[i]] = ra[i];
#pragma unroll
        for (int i = 0; i < 2; ++i) *(u16x8*)&Bb[0][boff[i]] = rb[i];
    }
    __syncthreads();

    const int swz0 = (quad ^ (c & 7)) * 8;
    const int swz1 = ((quad + 4) ^ (c & 7)) * 8;
#pragma unroll
    for (int ch = 0; ch < NCH; ++ch) {
        const int buf = ch % 3;
        // 1. issue global loads for chunk ch+2 into set (ch+1)&1
        if (ch + 2 < NCH) {
            const int kb = (ch + 2) * 64;
#pragma unroll
            for (int i = 0; i < ITA; ++i)
                pa[(ch + 1) & 1][i] =
                    *(const u16x8*)(aslab + (size_t)arow[i] * K + kb + ag);
#pragma unroll
            for (int i = 0; i < 2; ++i)
                pb[(ch + 1) & 1][i] =
                    *(const u16x8*)(bslab + (size_t)brow[i] * K + kb + ag);
        }
        // 2. compute chunk ch from LDS
        bf16x8 b0 = ldfrag(&Bb[buf][(wave * 16 + c) * 64 + swz0]);
        bf16x8 b1 = ldfrag(&Bb[buf][(wave * 16 + c) * 64 + swz1]);
#pragma unroll
        for (int mt = 0; mt < MT; ++mt) {
            bf16x8 a0 = ldfrag(&Ab[buf][(mt * 16 + c) * 64 + swz0]);
            bf16x8 a1 = ldfrag(&Ab[buf][(mt * 16 + c) * 64 + swz1]);
            acc[mt] = __builtin_amdgcn_mfma_f32_16x16x32_bf16(a0, b0, acc[mt], 0, 0, 0);
            acc[mt] = __builtin_amdgcn_mfma_f32_16x16x32_bf16(a1, b1, acc[mt], 0, 0, 0);
        }
        // 3. commit chunk ch+1 registers (loaded last iteration) to LDS
        if (ch + 1 < NCH) {
            const int nb = (ch + 1) % 3;
#pragma unroll
            for (int i = 0; i < ITA; ++i) *(u16x8*)&Ab[nb][aoff[i]] = pa[ch & 1][i];
#pragma unroll
            for (int i = 0; i < 2; ++i) *(u16x8*)&Bb[nb][boff[i]] = pb[ch & 1][i];
        }
        __syncthreads();
    }

    const int col = bn * 64 + wave * 16 + c;
    float bval = 0.f;
    if (bias) bval = (mode == 5) ? bias[(col >> 1) + (col & 1) * FFI] : bias[col];

    if (mode == 9) {  // transposed fp32 out + x residual (final fused), float4
#pragma unroll
        for (int mt = 0; mt < MT; ++mt) {
            const int row0 = m0 + mt * 16 + quad * 4;
            float4 xv = *(const float4*)(res + (size_t)col * HW + row0);
            float4 ov;
            ov.x = acc[mt][0] + bval + xv.x;
            ov.y = acc[mt][1] + bval + xv.y;
            ov.z = acc[mt][2] + bval + xv.z;
            ov.w = acc[mt][3] + bval + xv.w;
            *(float4*)((float*)Cout + (size_t)col * HW + row0) = ov;
        }
        return;
    }
#pragma unroll
    for (int mt = 0; mt < MT; ++mt) {
#pragma unroll
        for (int r = 0; r < 4; ++r) {
            const int row = m0 + mt * 16 + quad * 4 + r;
            float v = acc[mt][r];
            if (mode == 0) {
                v += bval;
                if (res) v += res[(size_t)row * N + col];
                ((float*)Cout)[(size_t)row * N + col] = v;
            } else if (mode == 2) {
                int h = col & 7, d = col >> 3;
                ((unsigned short*)Cout)[(((size_t)h << 12) + row) * 64 + d] = f2bf(v * scale);
            } else if (mode == 4) {
                ((unsigned short*)Cout)[(size_t)row * N + col] =
                    f2bf(v + bval + res[(size_t)row * N + col]);
            } else if (mode == 5) {
                v += bval;
                float other = __shfl_xor(v, 1, 64);
                if ((c & 1) == 0) {
                    float g = 0.5f * other * (1.f + erff(other * 0.70710678118654752f));
                    ((unsigned short*)Cout)[(size_t)row * FFI + (col >> 1)] = f2bf(v * g);
                }
            } else if (mode == 6) {
                ((unsigned short*)Cout)[(size_t)row * N + col] = f2bf(v);
                int h = col & 7, d = col >> 3;
                ((unsigned short*)Cout2)[(((size_t)h << 12) + row) * 64 + d] = f2bf(v * scale);
            } else if (mode == 7) {
                if (col < 320) {
                    int h = col & 7, d = col >> 3;
                    ((unsigned short*)Cout)[(((size_t)h << 12) + row) * 64 + d] = f2bf(v);
                } else {
                    int c2 = col - 320;
                    int h = c2 & 7, d = c2 >> 3;
                    ((unsigned short*)Cout2)[(((size_t)(h * 48 + d)) << 12) + row] = f2bf(v);
                }
            } else {  // 8: ctx kv-merged, Lkp = 128
                if (col < 320) {
                    int h = col & 7, d = col >> 3;
                    ((unsigned short*)Cout)[(((size_t)h << 7) + row) * 64 + d] = f2bf(v);
                } else {
                    int c2 = col - 320;
                    int h = c2 & 7, d = c2 >> 3;
                    ((unsigned short*)Cout2)[(size_t)(h * 48 + d) * 128 + row] = f2bf(v);
                }
            }
        }
    }
}

// ---------------------------------------------------------------------------
// Set V^T padded dim-40 row to 1.0 so sum(p) materializes in the PV MFMA.
__global__ void set_ones(unsigned short* __restrict__ Vt,
                         unsigned short* __restrict__ Vc) {
    int idx = blockIdx.x * 256 + threadIdx.x;  // grid 132 -> 33792 exact
    if (idx < 32768) {
        int h = idx >> 12, r = idx & 4095;
        Vt[((size_t)(h * 48 + 40) << 12) + r] = 0x3F80;  // bf16(1.0)
    } else {
        int j = idx - 32768;
        int h = j >> 7, r = j & 127;
        Vc[(h * 48 + 40) * 128 + r] = 0x3F80;
    }
}

// ---------------------------------------------------------------------------
// attn8: LDS-staged flash attention, 128 queries/block, k=16 PV (round-14).
template <int TILES, bool MASK>
__global__ __launch_bounds__(256) void attn8(
    const unsigned short* __restrict__ Qp,
    const unsigned short* __restrict__ Kp,
    const unsigned short* __restrict__ Vt,
    float* __restrict__ pO, float* __restrict__ pL,
    int Lk, int Lkp) {
    __shared__ __align__(16) unsigned short Kb[2][64 * 64];
    __shared__ __align__(16) unsigned short Vb[2][48 * 64];
    const int tid  = threadIdx.x;
    const int wave = tid >> 6, lane = tid & 63;
    const int quad = lane >> 4, c = lane & 15;
    const int id  = blockIdx.x;
    const int h   = id & 7;
    const int qt  = (id >> 3) & 31;
    const int seg = id >> 8;
    const int q0  = qt * 128 + wave * 32;

    const unsigned short* qbaseA = Qp + ((((size_t)h << 12) + q0 + c) << 6) + quad * 8;
    const bf16x8 bQA0 = ldfrag(qbaseA);
    const bf16x8 bQA1 = ldfrag(qbaseA + 32);
    const bf16x8 bQB0 = ldfrag(qbaseA + 1024);
    const bf16x8 bQB1 = ldfrag(qbaseA + 1024 + 32);

    f32x4 oA[3], oB[3];
#pragma unroll
    for (int i = 0; i < 3; ++i) {
        oA[i] = (f32x4){0.f, 0.f, 0.f, 0.f};
        oB[i] = (f32x4){0.f, 0.f, 0.f, 0.f};
    }

    const int kt0 = seg * TILES;
    const unsigned short* kglob = Kp + (((size_t)h * Lkp + kt0 * 64) << 6);
    const unsigned short* vglob = Vt + ((size_t)h * 48) * Lkp + kt0 * 64;

    const int r0 = lane >> 3;
    const int g  = lane & 7;
    int ldsoff[4];
    const unsigned short* gptr0[4];
#pragma unroll
    for (int i = 0; i < 4; ++i) {
        int s = wave + 4 * i;
        if (s < 8) {
            int row = s * 8 + r0;
            ldsoff[i] = row * 64 + (g ^ (row & 7)) * 8;
            gptr0[i]  = kglob + (size_t)row * 64 + g * 8;
        } else if (s < 14) {
            int d = (s - 8) * 8 + r0;
            ldsoff[i] = d * 64 + (g ^ (d & 7)) * 8;
            gptr0[i]  = vglob + (size_t)d * Lkp + g * 8;
        } else {
            ldsoff[i] = 0; gptr0[i] = nullptr;
        }
    }
    const bool isK[4] = {(wave + 0) < 8, (wave + 4) < 8, (wave + 8) < 8, (wave + 12) < 8};
    const bool act[4] = {true, true, true, (wave + 12) < 14};

    {
        u16x8 st[4];
#pragma unroll
        for (int i = 0; i < 4; ++i)
            if (act[i]) st[i] = *(const u16x8*)(gptr0[i]);
#pragma unroll
        for (int i = 0; i < 4; ++i)
            if (act[i]) {
                unsigned short* lp = isK[i] ? &Kb[0][ldsoff[i]] : &Vb[0][ldsoff[i]];
                *(u16x8*)lp = st[i];
            }
    }
    __syncthreads();

#pragma unroll
    for (int t = 0; t < TILES; ++t) {
        const int b = t & 1;
        u16x8 st[4];
        if (t + 1 < TILES) {
            const int kb = (t + 1) * 64;
#pragma unroll
            for (int i = 0; i < 4; ++i)
                if (act[i]) {
                    const unsigned short* gp =
                        isK[i] ? (gptr0[i] + (size_t)kb * 64) : (gptr0[i] + kb);
                    st[i] = *(const u16x8*)gp;
                }
        }
        const unsigned short* Kl = &Kb[b][0];
        const unsigned short* Vl = &Vb[b][0];
        const int sw0 = (quad ^ (c & 7)) * 8;
        const int sw1 = ((quad + 4) ^ (c & 7)) * 8;
        f32x4 sA[4], sB[4];
#pragma unroll
        for (int blk = 0; blk < 4; ++blk) {
            const int row = (blk * 16 + c) * 64;
            bf16x8 k0 = ldfrag(Kl + row + sw0);
            bf16x8 k1 = ldfrag(Kl + row + sw1);
            f32x4 zA = {0.f, 0.f, 0.f, 0.f};
            zA = __builtin_amdgcn_mfma_f32_16x16x32_bf16(k0, bQA0, zA, 0, 0, 0);
            zA = __builtin_amdgcn_mfma_f32_16x16x32_bf16(k1, bQA1, zA, 0, 0, 0);
            sA[blk] = zA;
            f32x4 zB = {0.f, 0.f, 0.f, 0.f};
            zB = __builtin_amdgcn_mfma_f32_16x16x32_bf16(k0, bQB0, zB, 0, 0, 0);
            zB = __builtin_amdgcn_mfma_f32_16x16x32_bf16(k1, bQB1, zB, 0, 0, 0);
            sB[blk] = zB;
        }
        if (MASK) {
            const int abs_kb = kt0 * 64 + t * 64;
#pragma unroll
            for (int blk = 0; blk < 4; ++blk)
#pragma unroll
                for (int r = 0; r < 4; ++r) {
                    bool inv = (abs_kb + blk * 16 + quad * 4 + r >= Lk);
                    sA[blk][r] = inv ? -30000.f : sA[blk][r];
                    sB[blk][r] = inv ? -30000.f : sB[blk][r];
                }
        }
        s16x4 PA[4], PB[4];
#pragma unroll
        for (int blk = 0; blk < 4; ++blk) {
            PA[blk] = pk2frag(pk2bf(exp2f(sA[blk][0]), exp2f(sA[blk][1])),
                              pk2bf(exp2f(sA[blk][2]), exp2f(sA[blk][3])));
            PB[blk] = pk2frag(pk2bf(exp2f(sB[blk][0]), exp2f(sB[blk][1])),
                              pk2bf(exp2f(sB[blk][2]), exp2f(sB[blk][3])));
        }
#pragma unroll
        for (int db = 0; db < 3; ++db) {
            const int dim = db * 16 + c;
            const unsigned short* vrow = Vl + dim * 64;
            const int dswz = dim & 7;
#pragma unroll
            for (int kb = 0; kb < 4; ++kb) {
                const int off = (((kb * 2 + (quad >> 1)) ^ dswz) * 8) + (quad & 1) * 4;
                s16x4 vf = *(const s16x4*)(vrow + off);
                oA[db] = __builtin_amdgcn_mfma_f32_16x16x16bf16_1k(vf, PA[kb], oA[db], 0, 0, 0);
                oB[db] = __builtin_amdgcn_mfma_f32_16x16x16bf16_1k(vf, PB[kb], oB[db], 0, 0, 0);
            }
        }
        if (t + 1 < TILES) {
            const int nb = b ^ 1;
#pragma unroll
            for (int i = 0; i < 4; ++i)
                if (act[i]) {
                    unsigned short* lp = isK[i] ? &Kb[nb][ldsoff[i]] : &Vb[nb][ldsoff[i]];
                    *(u16x8*)lp = st[i];
                }
        }
        __syncthreads();
    }
    const size_t base = ((size_t)(seg * 8 + h)) << 12;
    float* obA = pO + (base + q0 + c) * 40;
    *(float4*)(obA + quad * 4)      = make_float4(oA[0][0], oA[0][1], oA[0][2], oA[0][3]);
    *(float4*)(obA + 16 + quad * 4) = make_float4(oA[1][0], oA[1][1], oA[1][2], oA[1][3]);
    if (quad < 2)
        *(float4*)(obA + 32 + quad * 4) = make_float4(oA[2][0], oA[2][1], oA[2][2], oA[2][3]);
    float* obB = pO + (base + q0 + 16 + c) * 40;
    *(float4*)(obB + quad * 4)      = make_float4(oB[0][0], oB[0][1], oB[0][2], oB[0][3]);
    *(float4*)(obB + 16 + quad * 4) = make_float4(oB[1][0], oB[1][1], oB[1][2], oB[1][3]);
    if (quad < 2)
        *(float4*)(obB + 32 + quad * 4) = make_float4(oB[2][0], oB[2][1], oB[2][2], oB[2][3]);
    if (quad == 2) {
        pL[base + q0 + c]      = oA[2][0];
        pL[base + q0 + 16 + c] = oB[2][0];
    }
}

// Combine partials (vectorized): float4 loads, packed bf16 stores.
__global__ __launch_bounds__(256) void attn_combine2(
    const float* __restrict__ pO, const float* __restrict__ pL,
    unsigned short* __restrict__ O, int S) {
    int idx = blockIdx.x * 256 + threadIdx.x;  // < 8*4096*10, grid 1280
    int h = idx / (HW * 10);
    int rem = idx - h * (HW * 10);
    int row = rem / 10, dg = rem - row * 10;
    float4 num = make_float4(0.f, 0.f, 0.f, 0.f);
    float den = 0.f;
    for (int s = 0; s < S; ++s) {
        size_t base = ((size_t)(s * 8 + h)) << 12;
        float4 p = *(const float4*)(pO + (base + row) * 40 + dg * 4);
        num.x += p.x; num.y += p.y; num.z += p.z; num.w += p.w;
        den += pL[base + row];
    }
    float inv = 1.f / den;
    unsigned short* ob = O + (size_t)row * CCH + h * DH + dg * 4;
    unsigned lo = pk2bf(num.x * inv, num.y * inv);
    unsigned hi = pk2bf(num.z * inv, num.w * inv);
    *(uint2*)ob = make_uint2(lo, hi);
}

// ---------------------------------------------------------------------------
extern "C" void kernel_launch(void* const* d_in, const int* in_sizes, int n_in,
                              void* d_out, int out_size, void* d_ws, size_t ws_size,
                              hipStream_t stream) {
    const float* x     = (const float*)d_in[0];
    const float* ctx   = (const float*)d_in[1];
    const float* gn_w  = (const float*)d_in[2];
    const float* gn_b  = (const float*)d_in[3];
    const float* w_in  = (const float*)d_in[4];
    const float* b_in  = (const float*)d_in[5];
    const float* ln1_w = (const float*)d_in[6];
    const float* ln1_b = (const float*)d_in[7];
    const float* wq1   = (const float*)d_in[8];
    const float* wk1   = (const float*)d_in[9];
    const float* wv1   = (const float*)d_in[10];
    const float* wo1   = (const float*)d_in[11];
    const float* bo1   = (const float*)d_in[12];
    const float* ln2_w = (const float*)d_in[13];
    const float* ln2_b = (const float*)d_in[14];
    const float* wq2   = (const float*)d_in[15];
    const float* wk2   = (const float*)d_in[16];
    const float* wv2   = (const float*)d_in[17];
    const float* wo2   = (const float*)d_in[18];
    const float* bo2   = (const float*)d_in[19];
    const float* ln3_w = (const float*)d_in[20];
    const float* ln3_b = (const float*)d_in[21];
    const float* wff1  = (const float*)d_in[22];
    const float* bff1  = (const float*)d_in[23];
    const float* wff2  = (const float*)d_in[24];
    const float* bff2  = (const float*)d_in[25];
    const float* w_out = (const float*)d_in[26];
    const float* b_out = (const float*)d_in[27];
    float* out = (float*)d_out;

    const int NT = HW * CCH;  // 1,310,720
    float* ws = (float*)d_ws;
    float* t_   = ws;
    float* y_   = t_ + NT;   // (unused, layout stability)
    float* pO   = y_ + NT;
    float* pL   = pO + 4 * 8 * 4096 * 40;
    float2* gnp = (float2*)(pL + 4 * 8 * 4096);
    unsigned short* u = (unsigned short*)(gnp + 256);
    unsigned short* a_bf = u;                  u += NT;
    unsigned short* q_bf = u;                  u += NT;
    unsigned short* o_bf = u;                  u += NT;
    unsigned short* t_bf = u;                  u += NT;
    unsigned short* g_bf = u;                  u += HW * FFI;
    unsigned short* Qp   = u;                  u += 8 * 4096 * 64;
    unsigned short* Kp   = u;                  u += 8 * 4096 * 64;
    unsigned short* Vt   = u;                  u += 8 * 48 * 4096;
    unsigned short* Kc   = u;                  u += 8 * 128 * 64;
    unsigned short* Vc   = u;                  u += 8 * 48 * 128;
    unsigned short* Wt   = u;                  u += 2048000 + 2 * 245760;
    unsigned short* ctx_bf = u;                u += 128 * 768;

    const unsigned short* w_inT  = Wt;
    const unsigned short* wq1T   = Wt + 102400;
    const unsigned short* wk1T   = Wt + 204800;  // wv1T contiguous at +307200
    const unsigned short* wo1T   = Wt + 409600;
    const unsigned short* wq2T   = Wt + 512000;
    const unsigned short* wo2T   = Wt + 614400;
    const unsigned short* w_outT = Wt + 716800;
    const unsigned short* wff1T  = Wt + 819200;
    const unsigned short* wff2T  = Wt + 1638400;
    const unsigned short* wk2T   = Wt + 2048000;  // wv2T contiguous (N=640)

    const float qscale = 0.15811388300841897f * 1.4426950408889634f;  // 40^-.5 * log2e

    prep_w2<<<620, 256, 0, stream>>>(w_in, wq1, wk1, wv1, wo1, wq2, wo2, w_out,
                                     wff1, wff2, wk2, wv2, Wt);
    hipMemsetAsync(Qp, 0,
                   (size_t)(8 * 4096 * 64 * 2 + 8 * 48 * 4096 + 8 * 128 * 64 + 8 * 48 * 128) * 2,
                   stream);
    set_ones<<<132, 256, 0, stream>>>(Vt, Vc);
    pack_ctx<<<384, 256, 0, stream>>>(ctx, ctx_bf);

    // 1) GroupNorm -> a_bf (HW,C)
    gn_stats<<<256, 256, 0, stream>>>(x, gnp);
    gn_apply<<<dim3(64, 5), 256, 0, stream>>>(x, gnp, gn_w, gn_b, a_bf);
    // 2) proj_in: t = a @ w_in + b_in (fp32)
    gemm4<2, 320><<<dim3(5, 128), 256, 0, stream>>>(a_bf, w_inT, b_in, nullptr, t_, nullptr, CCH, 0, 1.f);
    // 3) ln1 -> a_bf
    ln_kernel<<<1024, 256, 0, stream>>>(t_, ln1_w, ln1_b, a_bf);
    // 4) q (dual); k&v in one N=640 dispatch
    gemm4<2, 320><<<dim3(5, 128), 256, 0, stream>>>(a_bf, wq1T, nullptr, nullptr, q_bf, Qp, CCH, 6, qscale);
    gemm4<2, 320><<<dim3(10, 128), 256, 0, stream>>>(q_bf, wk1T, nullptr, nullptr, Kp, Vt, 640, 7, 1.f);
    // 5) self-attention: 128 queries/block, 4 segs, XCD swizzle
    attn8<16, false><<<1024, 256, 0, stream>>>(Qp, Kp, Vt, pO, pL, HW, HW);
    attn_combine2<<<1280, 256, 0, stream>>>(pO, pL, o_bf, 4);
    // 6) t += o @ wo1 + bo1
    gemm4<2, 320><<<dim3(5, 128), 256, 0, stream>>>(o_bf, wo1T, bo1, t_, t_, nullptr, CCH, 0, 1.f);
    // 7) ln2 -> a_bf
    ln_kernel<<<1024, 256, 0, stream>>>(t_, ln2_w, ln2_b, a_bf);
    // 8) cross q -> Qp; ctx K/V via MFMA gemm (mode 8)
    gemm4<2, 320><<<dim3(5, 128), 256, 0, stream>>>(a_bf, wq2T, nullptr, nullptr, Qp, nullptr, CCH, 2, qscale);
    gemm4<2, 768><<<dim3(10, 4), 256, 0, stream>>>(ctx_bf, wk2T, nullptr, nullptr, Kc, Vc, 640, 8, 1.f);
    // 9) cross-attention (Lk=77, masked)
    attn8<2, true><<<256, 256, 0, stream>>>(Qp, Kc, Vc, pO, pL, 77, 128);
    attn_combine2<<<1280, 256, 0, stream>>>(pO, pL, o_bf, 1);
    // 10) t += o @ wo2 + bo2
    gemm4<2, 320><<<dim3(5, 128), 256, 0, stream>>>(o_bf, wo2T, bo2, t_, t_, nullptr, CCH, 0, 1.f);
    // 11) ln3 -> a_bf
    ln_kernel<<<1024, 256, 0, stream>>>(t_, ln3_w, ln3_b, a_bf);
    // 12+13) FF1 with fused GEGLU -> g_bf
    gemm4<2, 320><<<dim3(40, 128), 256, 0, stream>>>(a_bf, wff1T, bff1, nullptr, g_bf, nullptr, 2 * FFI, 5, 1.f);
    // 14) t_bf = bf16(t + g @ wff2 + bff2)
    gemm4<2, 1280><<<dim3(5, 128), 256, 0, stream>>>(g_bf, wff2T, bff2, t_, t_bf, nullptr, CCH, 4, 1.f);
    // 15+16) out = (t_bf @ w_out + b_out)^T + x  (final fused, mode 9)
    gemm4<2, 320><<<dim3(5, 128), 256, 0, stream>>>(t_bf, w_outT, b_out, x, out, nullptr, CCH, 9, 1.f);
}